// Round 15
// baseline (900.784 us; speedup 1.0000x reference)
//
#include <hip/hip_runtime.h>
#include <hip/hip_fp16.h>

#define NN 50000
#define EE 800000
#define GG 64
#define BNEPS 1e-5f

typedef _Float16 f16x8 __attribute__((ext_vector_type(8)));
typedef _Float16 f16x2 __attribute__((ext_vector_type(2)));
typedef float f32x4 __attribute__((ext_vector_type(4)));

__device__ inline float2 h2f(unsigned int u) {
    __half2 h = __builtin_bit_cast(__half2, u);
    return __half22float2(h);
}
__device__ inline unsigned int f2h(float a, float b) {
    __half2 h = __float22half2_rn(make_float2(a, b));
    return __builtin_bit_cast(unsigned int, h);
}
// relu on a packed half2 (this ROCm lacks __hmax2; scalar __hmax exists)
__device__ inline __half2 relu2(__half2 v) {
    const __half z = __float2half(0.f);
    return __halves2half2(__hmax(__low2half(v), z), __hmax(__high2half(v), z));
}
// f32 += lo(u)  /  f32 += hi(u)  via v_dot2_f32_f16 (exact: 1.0*h + 0.0*h)
__device__ inline float acc_lo(unsigned int u, float c) {
    return __builtin_amdgcn_fdot2(__builtin_bit_cast(f16x2, u),
                                  f16x2{(_Float16)1.f, (_Float16)0.f}, c, false);
}
__device__ inline float acc_hi(unsigned int u, float c) {
    return __builtin_amdgcn_fdot2(__builtin_bit_cast(f16x2, u),
                                  f16x2{(_Float16)0.f, (_Float16)1.f}, c, false);
}

// ---------------- CSR build ----------------

__global__ void hist_kernel(const int* __restrict__ ei, int* __restrict__ deg) {
    int e = blockIdx.x * 256 + threadIdx.x;
    if (e < EE) atomicAdd(&deg[ei[EE + e]], 1);
}

__global__ void scan1_kernel(const int* __restrict__ deg, int* __restrict__ offs,
                             int* __restrict__ bsum) {
    __shared__ int lds[1024];
    int i = blockIdx.x * 1024 + threadIdx.x;
    int v = (i < NN) ? deg[i] : 0;
    lds[threadIdx.x] = v;
    __syncthreads();
    for (int d = 1; d < 1024; d <<= 1) {
        int t = (threadIdx.x >= d) ? lds[threadIdx.x - d] : 0;
        __syncthreads();
        lds[threadIdx.x] += t;
        __syncthreads();
    }
    int incl = lds[threadIdx.x];
    if (i < NN) offs[i] = incl - v;
    if (threadIdx.x == 1023) bsum[blockIdx.x] = incl;
}

__global__ void scan3_kernel(int* __restrict__ offs, int* __restrict__ cursor,
                             const int* __restrict__ bsum) {
    __shared__ int base;
    if (threadIdx.x == 0) {
        int r = 0;
        for (int b = 0; b < (int)blockIdx.x; ++b) r += bsum[b];
        base = r;
    }
    __syncthreads();
    int i = blockIdx.x * 1024 + threadIdx.x;
    if (i < NN) {
        int o = offs[i] + base;
        offs[i] = o;
        cursor[i] = o;
    }
    if (i == 0 && blockIdx.x == 0) offs[NN] = EE;
}

// scatter v3: 8 blocks; block b exclusively owns dst slice [b*6250, (b+1)*6250).
// Each srcs region is written by exactly ONE workgroup -> its cache lines live in
// one L2 and write back once (no cross-XCD partial-line ping-pong). Each block
// scans all edges with int4 loads (L3-served after the first pass).

__global__ __launch_bounds__(1024) void scatter_kernel(const int* __restrict__ ei,
                                                       int* __restrict__ cursor,
                                                       unsigned short* __restrict__ srcs) {
    const int SLICE = NN / 8;  // 6250
    int lo = blockIdx.x * SLICE, hi = lo + SLICE;
    const int4* d4 = (const int4*)(ei + EE);
    const int4* s4 = (const int4*)ei;
    const int n4 = EE / 4;  // 200000
    for (int i = threadIdx.x; i < n4; i += 1024) {
        int4 d = d4[i];
        int4 s = s4[i];
        if (d.x >= lo && d.x < hi) {
            int p = atomicAdd(&cursor[d.x], 1);
            srcs[p] = (unsigned short)s.x;
        }
        if (d.y >= lo && d.y < hi) {
            int p = atomicAdd(&cursor[d.y], 1);
            srcs[p] = (unsigned short)s.y;
        }
        if (d.z >= lo && d.z < hi) {
            int p = atomicAdd(&cursor[d.z], 1);
            srcs[p] = (unsigned short)s.z;
        }
        if (d.w >= lo && d.w < hi) {
            int p = atomicAdd(&cursor[d.w], 1);
            srcs[p] = (unsigned short)s.w;
        }
    }
}

// ---------------- prep: fp32->fp16 convert of x_in + both weight packs, one launch -----

__device__ inline void packW_body(const float* Wl, __half* o_base, int t, int K, int C) {
    int NCF = C / 16;
    int kf = t / (NCF * 64), r2 = t % (NCF * 64);
    int cf = r2 >> 6, l = r2 & 63;
    __half* o = o_base + ((size_t)(kf * NCF + cf) * 64 + l) * 8;
    int k0 = kf * 32 + (l >> 4) * 8, c = cf * 16 + (l & 15);
#pragma unroll
    for (int j = 0; j < 8; ++j) o[j] = __float2half(Wl[(size_t)(k0 + j) * C + c]);
}

__global__ void prep_kernel(const float* __restrict__ in, __half* __restrict__ out,
                            const float* __restrict__ W1, __half* __restrict__ Wpk1,
                            const float* __restrict__ W2, __half* __restrict__ Wpk2) {
    const int CB = (NN * 16 + 255) / 256;  // cvt blocks
    int b = blockIdx.x;
    if (b < CB) {
        int i = b * 256 + threadIdx.x;
        if (i >= NN * 16) return;
        const float4* p = (const float4*)in + i * 2;
        float4 a = p[0], c = p[1];
        uint4 o;
        o.x = f2h(a.x, a.y);
        o.y = f2h(a.z, a.w);
        o.z = f2h(c.x, c.y);
        o.w = f2h(c.z, c.w);
        ((uint4*)out)[i] = o;
    } else if (b < CB + 28) {
        int t = (b - CB) * 256 + threadIdx.x;
        int layer = t >> 10, r = t & 1023;
        packW_body(W1 + (size_t)layer * 128 * 64, Wpk1 + (size_t)layer * 8192, r, 128, 64);
    } else {
        int t = (b - CB - 28) * 256 + threadIdx.x;
        int layer = t >> 10, r = t & 1023;
        packW_body(W2 + (size_t)layer * 64 * 128, Wpk2 + (size_t)layer * 8192, r, 64, 128);
    }
}

// ---------------- BN2+ReLU in place on fp16 y2 (N x 128), scale/shift from raw stats ---

__global__ __launch_bounds__(256) void bnrelu_kernel(__half* __restrict__ a,
                                                     const float* __restrict__ stats,
                                                     const float* __restrict__ bg,
                                                     const float* __restrict__ bb) {
    __shared__ float lsc[128], lsh[128];
    if (threadIdx.x < 128) {
        int c = threadIdx.x;
        float mu = stats[c] * (1.0f / NN);
        float var = stats[128 + c] * (1.0f / NN) - mu * mu;
        float inv = rsqrtf(var + BNEPS);
        float sc = bg[c] * inv;
        lsc[c] = sc;
        lsh[c] = bb[c] - mu * sc;
    }
    __syncthreads();
    const int total = NN * 16;  // uint4 chunks of 8 halves
    for (int t = blockIdx.x * 256 + threadIdx.x; t < total; t += gridDim.x * 256) {
        uint4 u = ((const uint4*)a)[t];
        int c0 = (t & 15) * 8;
        unsigned int* up = &u.x;
        uint4 o;
        unsigned int* op = &o.x;
#pragma unroll
        for (int j = 0; j < 4; ++j) {
            float2 f = h2f(up[j]);
            f.x = fmaxf(fmaf(f.x, lsc[c0 + 2 * j], lsh[c0 + 2 * j]), 0.f);
            f.y = fmaxf(fmaf(f.y, lsc[c0 + 2 * j + 1], lsh[c0 + 2 * j + 1]), 0.f);
            op[j] = f2h(f.x, f.y);
        }
        ((uint4*)a)[t] = o;
    }
}

// ---------------- GIN aggregation over fp16 rows (inputs already activated) ----------
// wave = 1 node. lane = (g,l): g=lane>>3 edge slot (8), l=lane&7 dim chunk (32B).
// Depth-2 prefetch (2x 32B/lane in flight); fdot2 accumulate.

__global__ __launch_bounds__(256) void agg_kernel(const __half* __restrict__ x,
                                                  const int* __restrict__ offs,
                                                  const unsigned short* __restrict__ srcs,
                                                  const float* __restrict__ epsp, int layer,
                                                  __half* __restrict__ h0) {
    int node = blockIdx.x * 4 + (threadIdx.x >> 6);
    if (node >= NN) return;
    int lane = threadIdx.x & 63;
    int g = lane >> 3;
    int l = lane & 7;
    float acc[16];
#pragma unroll
    for (int j = 0; j < 16; ++j) acc[j] = 0.f;

    int beg = offs[node], end = offs[node + 1];
    int i0 = beg + g, i1 = i0 + 8;
    int s0 = (i0 < end) ? (int)srcs[i0] : 0;
    int s1 = (i1 < end) ? (int)srcs[i1] : 0;
    const uint4* r0 = (const uint4*)(x + (size_t)s0 * 128) + l * 2;
    const uint4* r1 = (const uint4*)(x + (size_t)s1 * 128) + l * 2;
    uint4 va = r0[0], vb = r0[1];
    uint4 wa = r1[0], wb = r1[1];
    // self row issued early (used after the loop)
    const uint4* sp = (const uint4*)(x + (size_t)node * 128) + l * 2;
    uint4 xa, xb;
    if (g == 0) {
        xa = sp[0];
        xb = sp[1];
    }
    for (int base = beg; base + g < end; base += 8) {
        int i2 = base + 16 + g;
        int sP = (i2 < end) ? (int)srcs[i2] : 0;
        const uint4* r2 = (const uint4*)(x + (size_t)sP * 128) + l * 2;
        uint4 ua = r2[0], ub = r2[1];  // round t+2 in flight
#pragma unroll
        for (int j = 0; j < 8; ++j) {
            unsigned int u = (j == 0) ? va.x : (j == 1) ? va.y : (j == 2) ? va.z
                             : (j == 3) ? va.w : (j == 4) ? vb.x : (j == 5) ? vb.y
                             : (j == 6) ? vb.z : vb.w;
            acc[2 * j] = acc_lo(u, acc[2 * j]);
            acc[2 * j + 1] = acc_hi(u, acc[2 * j + 1]);
        }
        va = wa; vb = wb;
        wa = ua; wb = ub;
    }
    float e1 = 1.0f + epsp[layer];
    if (g == 0) {
#pragma unroll
        for (int j = 0; j < 8; ++j) {
            unsigned int u = (j == 0) ? xa.x : (j == 1) ? xa.y : (j == 2) ? xa.z
                             : (j == 3) ? xa.w : (j == 4) ? xb.x : (j == 5) ? xb.y
                             : (j == 6) ? xb.z : xb.w;
            float2 f = h2f(u);
            acc[2 * j] = fmaf(e1, f.x, acc[2 * j]);
            acc[2 * j + 1] = fmaf(e1, f.y, acc[2 * j + 1]);
        }
    }
#pragma unroll
    for (int d = 8; d < 64; d <<= 1)
#pragma unroll
        for (int j = 0; j < 16; ++j) acc[j] += __shfl_xor(acc[j], d);
    if (g == 0) {
        uint4 o0, o1;
        o0.x = f2h(acc[0], acc[1]);
        o0.y = f2h(acc[2], acc[3]);
        o0.z = f2h(acc[4], acc[5]);
        o0.w = f2h(acc[6], acc[7]);
        o1.x = f2h(acc[8], acc[9]);
        o1.y = f2h(acc[10], acc[11]);
        o1.z = f2h(acc[12], acc[13]);
        o1.w = f2h(acc[14], acc[15]);
        uint4* o = (uint4*)(h0 + (size_t)node * 128 + l * 16);
        o[0] = o0;
        o[1] = o1;
    }
}

// ---------------- GEMM1 (MFMA, grid-stride): y1 = h0 @ W1 -> fp16 + stats -------------

__global__ __launch_bounds__(256) void gemm1_kernel(const __half* __restrict__ h0,
                                                    const __half* __restrict__ Wpk,
                                                    __half* __restrict__ y,
                                                    float* __restrict__ stats) {
    int lane = threadIdx.x & 63, wave = threadIdx.x >> 6, g = lane >> 4;
    f16x8 bf[4][4];
    const f16x8* wp = (const f16x8*)Wpk;
#pragma unroll
    for (int kf = 0; kf < 4; ++kf)
#pragma unroll
        for (int cf = 0; cf < 4; ++cf) bf[kf][cf] = wp[(kf * 4 + cf) * 64 + lane];
    float s[4] = {0.f, 0.f, 0.f, 0.f}, s2[4] = {0.f, 0.f, 0.f, 0.f};
    for (int tile = blockIdx.x * 4 + wave; tile < NN / 16; tile += gridDim.x * 4) {
        int node16 = tile * 16;
        f32x4 acc[4];
#pragma unroll
        for (int cf = 0; cf < 4; ++cf) acc[cf] = (f32x4){0.f, 0.f, 0.f, 0.f};
        const f16x8* xr = (const f16x8*)(h0 + (size_t)(node16 + (lane & 15)) * 128);
#pragma unroll
        for (int kf = 0; kf < 4; ++kf) {
            f16x8 af = xr[kf * 4 + g];
#pragma unroll
            for (int cf = 0; cf < 4; ++cf)
                acc[cf] =
                    __builtin_amdgcn_mfma_f32_16x16x32_f16(af, bf[kf][cf], acc[cf], 0, 0, 0);
        }
#pragma unroll
        for (int cf = 0; cf < 4; ++cf) {
#pragma unroll
            for (int r = 0; r < 4; ++r) {
                float v = acc[cf][r];
                float p = __shfl_xor(v, 1);
                if (!(lane & 1)) {
                    int node = node16 + g * 4 + r;
                    int ch = cf * 16 + (lane & 15);
                    *(unsigned int*)(y + (size_t)node * 64 + ch) = f2h(v, p);
                }
                s[cf] += v;
                s2[cf] += v * v;
            }
        }
    }
#pragma unroll
    for (int d = 16; d < 64; d <<= 1)
#pragma unroll
        for (int cf = 0; cf < 4; ++cf) {
            s[cf] += __shfl_xor(s[cf], d);
            s2[cf] += __shfl_xor(s2[cf], d);
        }
    __shared__ float lst[4][128];
    if (lane < 16) {
#pragma unroll
        for (int cf = 0; cf < 4; ++cf) {
            lst[wave][cf * 16 + lane] = s[cf];
            lst[wave][64 + cf * 16 + lane] = s2[cf];
        }
    }
    __syncthreads();
    if (threadIdx.x < 128)
        atomicAdd(&stats[threadIdx.x], lst[0][threadIdx.x] + lst[1][threadIdx.x] +
                                           lst[2][threadIdx.x] + lst[3][threadIdx.x]);
}

// ---------------- GEMM2 (MFMA, grid-stride): y2 = relu(bn1(y1)) @ W2 -> fp16 + stats ---

__global__ __launch_bounds__(256) void gemm2_kernel(const __half* __restrict__ y1,
                                                    const __half* __restrict__ Wpk,
                                                    const float* __restrict__ stats1,
                                                    const float* __restrict__ bg,
                                                    const float* __restrict__ bb,
                                                    __half* __restrict__ y2,
                                                    float* __restrict__ stats2) {
    __shared__ __half2 lsc2[32], lsh2[32];
    if (threadIdx.x < 32) {
        int p = threadIdx.x;
        int c0 = 2 * p, c1 = 2 * p + 1;
        float mu0 = stats1[c0] * (1.0f / NN);
        float var0 = stats1[64 + c0] * (1.0f / NN) - mu0 * mu0;
        float is0 = rsqrtf(var0 + BNEPS);
        float sc0 = bg[c0] * is0;
        float mu1 = stats1[c1] * (1.0f / NN);
        float var1 = stats1[64 + c1] * (1.0f / NN) - mu1 * mu1;
        float is1 = rsqrtf(var1 + BNEPS);
        float sc1 = bg[c1] * is1;
        lsc2[p] = __floats2half2_rn(sc0, sc1);
        lsh2[p] = __floats2half2_rn(bb[c0] - mu0 * sc0, bb[c1] - mu1 * sc1);
    }
    __syncthreads();
    int lane = threadIdx.x & 63, wave = threadIdx.x >> 6, g = lane >> 4;
    f16x8 bf[2][8];
    const f16x8* wp = (const f16x8*)Wpk;
#pragma unroll
    for (int kf = 0; kf < 2; ++kf)
#pragma unroll
        for (int cf = 0; cf < 8; ++cf) bf[kf][cf] = wp[(kf * 8 + cf) * 64 + lane];
    float s[8] = {0.f, 0.f, 0.f, 0.f, 0.f, 0.f, 0.f, 0.f};
    float s2[8] = {0.f, 0.f, 0.f, 0.f, 0.f, 0.f, 0.f, 0.f};
    for (int tile = blockIdx.x * 4 + wave; tile < NN / 16; tile += gridDim.x * 4) {
        int node16 = tile * 16;
        f32x4 acc[8];
#pragma unroll
        for (int cf = 0; cf < 8; ++cf) acc[cf] = (f32x4){0.f, 0.f, 0.f, 0.f};
        const f16x8* xr = (const f16x8*)(y1 + (size_t)(node16 + (lane & 15)) * 64);
#pragma unroll
        for (int kf = 0; kf < 2; ++kf) {
            f16x8 af = xr[kf * 4 + g];
            __half2* ap = (__half2*)&af;
            int p0 = kf * 16 + g * 4;
#pragma unroll
            for (int j = 0; j < 4; ++j)
                ap[j] = relu2(__hfma2(ap[j], lsc2[p0 + j], lsh2[p0 + j]));
#pragma unroll
            for (int cf = 0; cf < 8; ++cf)
                acc[cf] =
                    __builtin_amdgcn_mfma_f32_16x16x32_f16(af, bf[kf][cf], acc[cf], 0, 0, 0);
        }
#pragma unroll
        for (int cf = 0; cf < 8; ++cf) {
#pragma unroll
            for (int r = 0; r < 4; ++r) {
                float v = acc[cf][r];
                float p = __shfl_xor(v, 1);
                if (!(lane & 1)) {
                    int node = node16 + g * 4 + r;
                    int ch = cf * 16 + (lane & 15);
                    *(unsigned int*)(y2 + (size_t)node * 128 + ch) = f2h(v, p);
                }
                s[cf] += v;
                s2[cf] += v * v;
            }
        }
    }
#pragma unroll
    for (int d = 16; d < 64; d <<= 1)
#pragma unroll
        for (int cf = 0; cf < 8; ++cf) {
            s[cf] += __shfl_xor(s[cf], d);
            s2[cf] += __shfl_xor(s2[cf], d);
        }
    __shared__ float lst[4][256];
    if (lane < 16) {
#pragma unroll
        for (int cf = 0; cf < 8; ++cf) {
            lst[wave][cf * 16 + lane] = s[cf];
            lst[wave][128 + cf * 16 + lane] = s2[cf];
        }
    }
    __syncthreads();
    atomicAdd(&stats2[threadIdx.x], lst[0][threadIdx.x] + lst[1][threadIdx.x] +
                                        lst[2][threadIdx.x] + lst[3][threadIdx.x]);
}

// ---------------- last layer + fused mean-pool accumulation ----------------

__global__ void gemm_last_kernel(const __half* __restrict__ y1, const float* __restrict__ W,
                                 const float* __restrict__ stats1,
                                 const float* __restrict__ bg, const float* __restrict__ bb,
                                 const int* __restrict__ batch, float* __restrict__ pool) {
    __shared__ float lw[128];
    __shared__ float lsc[64], lsh[64];
    if (threadIdx.x < 128) lw[threadIdx.x] = W[threadIdx.x];
    if (threadIdx.x < 64) {
        int c = threadIdx.x;
        float mu = stats1[c] * (1.0f / NN);
        float var = stats1[64 + c] * (1.0f / NN) - mu * mu;
        float inv = rsqrtf(var + BNEPS);
        float sc = bg[c] * inv;
        lsc[c] = sc;
        lsh[c] = bb[c] - mu * sc;
    }
    __syncthreads();
    int n = blockIdx.x * 256 + threadIdx.x;
    int lane = threadIdx.x & 63;
    int gID = -1;
    float v0 = 0.f, v1 = 0.f, cnt = 0.f;
    if (n < NN) {
        float a0 = 0.f, a1 = 0.f;
        const uint4* row = (const uint4*)(y1 + (size_t)n * 64);
#pragma unroll
        for (int c8 = 0; c8 < 8; ++c8) {
            uint4 u = row[c8];
#pragma unroll
            for (int j = 0; j < 4; ++j) {
                unsigned int w = (j == 0) ? u.x : (j == 1) ? u.y : (j == 2) ? u.z : u.w;
                float2 f = h2f(w);
                int k = c8 * 8 + j * 2;
                float t0 = fmaxf(fmaf(f.x, lsc[k], lsh[k]), 0.f);
                float t1 = fmaxf(fmaf(f.y, lsc[k + 1], lsh[k + 1]), 0.f);
                a0 = fmaf(t0, lw[2 * k + 0], a0);
                a1 = fmaf(t0, lw[2 * k + 1], a1);
                a0 = fmaf(t1, lw[2 * k + 2], a0);
                a1 = fmaf(t1, lw[2 * k + 3], a1);
            }
        }
        gID = batch[n];
        v0 = fmaxf(a0, 0.f);
        v1 = fmaxf(a1, 0.f);
        cnt = 1.0f;
    }
    for (int d = 1; d < 64; d <<= 1) {
        int tg = __shfl_up(gID, d);
        float t0 = __shfl_up(v0, d);
        float t1 = __shfl_up(v1, d);
        float tc = __shfl_up(cnt, d);
        if (lane >= d && tg == gID) { v0 += t0; v1 += t1; cnt += tc; }
    }
    int gn = __shfl_down(gID, 1);
    bool lastv = (lane == 63) || (gn != gID);
    if (gID >= 0 && lastv) {
        atomicAdd(&pool[gID * 3 + 0], v0);
        atomicAdd(&pool[gID * 3 + 1], v1);
        atomicAdd(&pool[gID * 3 + 2], cnt);
    }
}

__global__ void pool_fin_kernel(const float* __restrict__ pool, float* __restrict__ out) {
    int t = threadIdx.x;
    if (t < GG * 2) {
        int g = t >> 1, j = t & 1;
        float cnt = pool[g * 3 + 2];
        out[t] = pool[g * 3 + j] / fmaxf(cnt, 1.0f);
    }
}

// ---------------- launch ----------------

extern "C" void kernel_launch(void* const* d_in, const int* in_sizes, int n_in,
                              void* d_out, int out_size, void* d_ws, size_t ws_size,
                              hipStream_t stream) {
    const float* x_in  = (const float*)d_in[0];
    const int*   ei    = (const int*)d_in[1];
    const int*   batch = (const int*)d_in[3];
    const float* W1    = (const float*)d_in[4];
    const float* bn1g  = (const float*)d_in[5];
    const float* bn1b  = (const float*)d_in[6];
    const float* W2    = (const float*)d_in[7];
    const float* bn2g  = (const float*)d_in[8];
    const float* bn2b  = (const float*)d_in[9];
    const float* Wlast = (const float*)d_in[10];
    const float* eps   = (const float*)d_in[11];
    float* out = (float*)d_out;

    char* ws = (char*)d_ws;
    size_t off = 0;
    auto alloc = [&](size_t bytes) -> char* {
        char* p = ws + off;
        off += (bytes + 255) & ~(size_t)255;
        return p;
    };
    // -- zeroed region first (one memset) --
    int*   deg      = (int*)alloc((size_t)NN * 4);
    float* statsall = (float*)alloc(16 * 256 * 4);  // slot s: [0..C) sum, [C..2C) sumsq
    float* pool     = (float*)alloc((size_t)GG * 3 * 4);
    size_t zero_len = off;
    // -- rest --
    int*            offs   = (int*)alloc((size_t)(NN + 1) * 4);
    int*            cursor = (int*)alloc((size_t)NN * 4);
    int*            bsum   = (int*)alloc(64 * 4);
    unsigned short* srcs   = (unsigned short*)alloc((size_t)EE * 2);
    __half*         X16    = (__half*)alloc((size_t)NN * 128 * 2);  // fp16 x_in
    __half*         A16    = (__half*)alloc((size_t)NN * 128 * 2);  // fp16 y2 (activated)
    __half*         B16    = (__half*)alloc((size_t)NN * 128 * 2);  // fp16 h0
    __half*         C16    = (__half*)alloc((size_t)NN * 64 * 2);   // fp16 raw y1
    __half*         Wpk1   = (__half*)alloc((size_t)7 * 8192 * 2);  // packed W1 frags
    __half*         Wpk2   = (__half*)alloc((size_t)6 * 8192 * 2);  // packed W2 frags
    (void)ws_size; (void)n_in; (void)in_sizes; (void)out_size;

    hipMemsetAsync(ws, 0, zero_len, stream);

    // CSR build (by dst) + prep (cvt + weight packs, one launch)
    hist_kernel<<<(EE + 255) / 256, 256, 0, stream>>>(ei, deg);
    scan1_kernel<<<49, 1024, 0, stream>>>(deg, offs, bsum);
    scan3_kernel<<<49, 1024, 0, stream>>>(offs, cursor, bsum);
    scatter_kernel<<<8, 1024, 0, stream>>>(ei, cursor, srcs);
    const int CB = (NN * 16 + 255) / 256;
    prep_kernel<<<CB + 28 + 24, 256, 0, stream>>>(x_in, X16, W1, Wpk1, W2, Wpk2);

    for (int i = 0; i < 7; ++i) {
        int s1 = 2 * i, s2 = 2 * i + 1;
        agg_kernel<<<(NN + 3) / 4, 256, 0, stream>>>(i == 0 ? X16 : A16, offs, srcs, eps, i,
                                                     B16);
        gemm1_kernel<<<256, 256, 0, stream>>>(B16, Wpk1 + (size_t)i * 8192, C16,
                                              statsall + s1 * 256);
        if (i < 6) {
            gemm2_kernel<<<256, 256, 0, stream>>>(C16, Wpk2 + (size_t)i * 8192,
                                                  statsall + s1 * 256, bn1g + i * 64,
                                                  bn1b + i * 64, A16, statsall + s2 * 256);
            bnrelu_kernel<<<2048, 256, 0, stream>>>(A16, statsall + s2 * 256,
                                                    bn2g + i * 128, bn2b + i * 128);
        } else {
            gemm_last_kernel<<<(NN + 255) / 256, 256, 0, stream>>>(
                C16, Wlast, statsall + s1 * 256, bn1g + i * 64, bn1b + i * 64, batch, pool);
        }
    }

    pool_fin_kernel<<<1, 128, 0, stream>>>(pool, out);
}

// Round 16
// 559.438 us; speedup vs baseline: 1.6102x; 1.6102x over previous
//
#include <hip/hip_runtime.h>
#include <hip/hip_fp16.h>

#define NN 50000
#define EE 800000
#define GG 64
#define BNEPS 1e-5f

typedef _Float16 f16x8 __attribute__((ext_vector_type(8)));
typedef _Float16 f16x2 __attribute__((ext_vector_type(2)));
typedef float f32x4 __attribute__((ext_vector_type(4)));

__device__ inline float2 h2f(unsigned int u) {
    __half2 h = __builtin_bit_cast(__half2, u);
    return __half22float2(h);
}
__device__ inline unsigned int f2h(float a, float b) {
    __half2 h = __float22half2_rn(make_float2(a, b));
    return __builtin_bit_cast(unsigned int, h);
}
// relu on a packed half2 (this ROCm lacks __hmax2; scalar __hmax exists)
__device__ inline __half2 relu2(__half2 v) {
    const __half z = __float2half(0.f);
    return __halves2half2(__hmax(__low2half(v), z), __hmax(__high2half(v), z));
}
// f32 += lo(u)  /  f32 += hi(u)  via v_dot2_f32_f16 (exact: 1.0*h + 0.0*h)
__device__ inline float acc_lo(unsigned int u, float c) {
    return __builtin_amdgcn_fdot2(__builtin_bit_cast(f16x2, u),
                                  f16x2{(_Float16)1.f, (_Float16)0.f}, c, false);
}
__device__ inline float acc_hi(unsigned int u, float c) {
    return __builtin_amdgcn_fdot2(__builtin_bit_cast(f16x2, u),
                                  f16x2{(_Float16)0.f, (_Float16)1.f}, c, false);
}

// ---------------- CSR build ----------------

__global__ void hist_kernel(const int* __restrict__ ei, int* __restrict__ deg) {
    int e = blockIdx.x * 256 + threadIdx.x;
    if (e < EE) atomicAdd(&deg[ei[EE + e]], 1);
}

__global__ void scan1_kernel(const int* __restrict__ deg, int* __restrict__ offs,
                             int* __restrict__ bsum) {
    __shared__ int lds[1024];
    int i = blockIdx.x * 1024 + threadIdx.x;
    int v = (i < NN) ? deg[i] : 0;
    lds[threadIdx.x] = v;
    __syncthreads();
    for (int d = 1; d < 1024; d <<= 1) {
        int t = (threadIdx.x >= d) ? lds[threadIdx.x - d] : 0;
        __syncthreads();
        lds[threadIdx.x] += t;
        __syncthreads();
    }
    int incl = lds[threadIdx.x];
    if (i < NN) offs[i] = incl - v;
    if (threadIdx.x == 1023) bsum[blockIdx.x] = incl;
}

__global__ void scan3_kernel(int* __restrict__ offs, int* __restrict__ cursor,
                             const int* __restrict__ bsum) {
    __shared__ int base;
    if (threadIdx.x == 0) {
        int r = 0;
        for (int b = 0; b < (int)blockIdx.x; ++b) r += bsum[b];
        base = r;
    }
    __syncthreads();
    int i = blockIdx.x * 1024 + threadIdx.x;
    if (i < NN) {
        int o = offs[i] + base;
        offs[i] = o;
        cursor[i] = o;
    }
    if (i == 0 && blockIdx.x == 0) offs[NN] = EE;
}

// ---------------- scatter + prep merged: independent work, one dispatch ----------------
// blocks [0, SB): edge scatter; [SB, SB+CB): x_in cvt; then W1/W2 packs.

__device__ inline void packW_body(const float* Wl, __half* o_base, int t, int K, int C) {
    int NCF = C / 16;
    int kf = t / (NCF * 64), r2 = t % (NCF * 64);
    int cf = r2 >> 6, l = r2 & 63;
    __half* o = o_base + ((size_t)(kf * NCF + cf) * 64 + l) * 8;
    int k0 = kf * 32 + (l >> 4) * 8, c = cf * 16 + (l & 15);
#pragma unroll
    for (int j = 0; j < 8; ++j) o[j] = __float2half(Wl[(size_t)(k0 + j) * C + c]);
}

__global__ void scatter_prep_kernel(const int* __restrict__ ei, int* __restrict__ cursor,
                                    unsigned short* __restrict__ srcs,
                                    const float* __restrict__ in, __half* __restrict__ out,
                                    const float* __restrict__ W1, __half* __restrict__ Wpk1,
                                    const float* __restrict__ W2, __half* __restrict__ Wpk2) {
    const int SB = (EE + 255) / 256;       // scatter blocks: 3125
    const int CB = (NN * 16 + 255) / 256;  // cvt blocks: 3125
    int b = blockIdx.x;
    if (b < SB) {
        int e = b * 256 + threadIdx.x;
        if (e < EE) {
            int s = ei[e];
            int d = ei[EE + e];
            int pos = atomicAdd(&cursor[d], 1);
            srcs[pos] = (unsigned short)s;
        }
    } else if (b < SB + CB) {
        int i = (b - SB) * 256 + threadIdx.x;
        if (i >= NN * 16) return;
        const float4* p = (const float4*)in + i * 2;
        float4 a = p[0], c = p[1];
        uint4 o;
        o.x = f2h(a.x, a.y);
        o.y = f2h(a.z, a.w);
        o.z = f2h(c.x, c.y);
        o.w = f2h(c.z, c.w);
        ((uint4*)out)[i] = o;
    } else if (b < SB + CB + 28) {
        int t = (b - SB - CB) * 256 + threadIdx.x;
        int layer = t >> 10, r = t & 1023;
        packW_body(W1 + (size_t)layer * 128 * 64, Wpk1 + (size_t)layer * 8192, r, 128, 64);
    } else {
        int t = (b - SB - CB - 28) * 256 + threadIdx.x;
        int layer = t >> 10, r = t & 1023;
        packW_body(W2 + (size_t)layer * 64 * 128, Wpk2 + (size_t)layer * 8192, r, 64, 128);
    }
}

// ---------------- BN2+ReLU in place on fp16 y2 (N x 128), scale/shift from raw stats ---

__global__ __launch_bounds__(256) void bnrelu_kernel(__half* __restrict__ a,
                                                     const float* __restrict__ stats,
                                                     const float* __restrict__ bg,
                                                     const float* __restrict__ bb) {
    __shared__ float lsc[128], lsh[128];
    if (threadIdx.x < 128) {
        int c = threadIdx.x;
        float mu = stats[c] * (1.0f / NN);
        float var = stats[128 + c] * (1.0f / NN) - mu * mu;
        float inv = rsqrtf(var + BNEPS);
        float sc = bg[c] * inv;
        lsc[c] = sc;
        lsh[c] = bb[c] - mu * sc;
    }
    __syncthreads();
    const int total = NN * 16;  // uint4 chunks of 8 halves
    for (int t = blockIdx.x * 256 + threadIdx.x; t < total; t += gridDim.x * 256) {
        uint4 u = ((const uint4*)a)[t];
        int c0 = (t & 15) * 8;
        unsigned int* up = &u.x;
        uint4 o;
        unsigned int* op = &o.x;
#pragma unroll
        for (int j = 0; j < 4; ++j) {
            float2 f = h2f(up[j]);
            f.x = fmaxf(fmaf(f.x, lsc[c0 + 2 * j], lsh[c0 + 2 * j]), 0.f);
            f.y = fmaxf(fmaf(f.y, lsc[c0 + 2 * j + 1], lsh[c0 + 2 * j + 1]), 0.f);
            op[j] = f2h(f.x, f.y);
        }
        ((uint4*)a)[t] = o;
    }
}

// ---------------- GIN aggregation over fp16 rows (inputs already activated) ----------
// wave = 1 node. lane = (g,l): g=lane>>3 edge slot (8), l=lane&7 dim chunk (32B).
// Depth-2 prefetch (2x 32B/lane in flight); fdot2 accumulate.

__global__ __launch_bounds__(256) void agg_kernel(const __half* __restrict__ x,
                                                  const int* __restrict__ offs,
                                                  const unsigned short* __restrict__ srcs,
                                                  const float* __restrict__ epsp, int layer,
                                                  __half* __restrict__ h0) {
    int node = blockIdx.x * 4 + (threadIdx.x >> 6);
    if (node >= NN) return;
    int lane = threadIdx.x & 63;
    int g = lane >> 3;
    int l = lane & 7;
    float acc[16];
#pragma unroll
    for (int j = 0; j < 16; ++j) acc[j] = 0.f;

    int beg = offs[node], end = offs[node + 1];
    int i0 = beg + g, i1 = i0 + 8;
    int s0 = (i0 < end) ? (int)srcs[i0] : 0;
    int s1 = (i1 < end) ? (int)srcs[i1] : 0;
    const uint4* r0 = (const uint4*)(x + (size_t)s0 * 128) + l * 2;
    const uint4* r1 = (const uint4*)(x + (size_t)s1 * 128) + l * 2;
    uint4 va = r0[0], vb = r0[1];
    uint4 wa = r1[0], wb = r1[1];
    // self row issued early (used after the loop)
    const uint4* sp = (const uint4*)(x + (size_t)node * 128) + l * 2;
    uint4 xa, xb;
    if (g == 0) {
        xa = sp[0];
        xb = sp[1];
    }
    for (int base = beg; base + g < end; base += 8) {
        int i2 = base + 16 + g;
        int sP = (i2 < end) ? (int)srcs[i2] : 0;
        const uint4* r2 = (const uint4*)(x + (size_t)sP * 128) + l * 2;
        uint4 ua = r2[0], ub = r2[1];  // round t+2 in flight
#pragma unroll
        for (int j = 0; j < 8; ++j) {
            unsigned int u = (j == 0) ? va.x : (j == 1) ? va.y : (j == 2) ? va.z
                             : (j == 3) ? va.w : (j == 4) ? vb.x : (j == 5) ? vb.y
                             : (j == 6) ? vb.z : vb.w;
            acc[2 * j] = acc_lo(u, acc[2 * j]);
            acc[2 * j + 1] = acc_hi(u, acc[2 * j + 1]);
        }
        va = wa; vb = wb;
        wa = ua; wb = ub;
    }
    float e1 = 1.0f + epsp[layer];
    if (g == 0) {
#pragma unroll
        for (int j = 0; j < 8; ++j) {
            unsigned int u = (j == 0) ? xa.x : (j == 1) ? xa.y : (j == 2) ? xa.z
                             : (j == 3) ? xa.w : (j == 4) ? xb.x : (j == 5) ? xb.y
                             : (j == 6) ? xb.z : xb.w;
            float2 f = h2f(u);
            acc[2 * j] = fmaf(e1, f.x, acc[2 * j]);
            acc[2 * j + 1] = fmaf(e1, f.y, acc[2 * j + 1]);
        }
    }
#pragma unroll
    for (int d = 8; d < 64; d <<= 1)
#pragma unroll
        for (int j = 0; j < 16; ++j) acc[j] += __shfl_xor(acc[j], d);
    if (g == 0) {
        uint4 o0, o1;
        o0.x = f2h(acc[0], acc[1]);
        o0.y = f2h(acc[2], acc[3]);
        o0.z = f2h(acc[4], acc[5]);
        o0.w = f2h(acc[6], acc[7]);
        o1.x = f2h(acc[8], acc[9]);
        o1.y = f2h(acc[10], acc[11]);
        o1.z = f2h(acc[12], acc[13]);
        o1.w = f2h(acc[14], acc[15]);
        uint4* o = (uint4*)(h0 + (size_t)node * 128 + l * 16);
        o[0] = o0;
        o[1] = o1;
    }
}

// ---------------- GEMM1 (MFMA, grid-stride): y1 = h0 @ W1 -> fp16 + stats -------------

__global__ __launch_bounds__(256) void gemm1_kernel(const __half* __restrict__ h0,
                                                    const __half* __restrict__ Wpk,
                                                    __half* __restrict__ y,
                                                    float* __restrict__ stats) {
    int lane = threadIdx.x & 63, wave = threadIdx.x >> 6, g = lane >> 4;
    f16x8 bf[4][4];
    const f16x8* wp = (const f16x8*)Wpk;
#pragma unroll
    for (int kf = 0; kf < 4; ++kf)
#pragma unroll
        for (int cf = 0; cf < 4; ++cf) bf[kf][cf] = wp[(kf * 4 + cf) * 64 + lane];
    float s[4] = {0.f, 0.f, 0.f, 0.f}, s2[4] = {0.f, 0.f, 0.f, 0.f};
    for (int tile = blockIdx.x * 4 + wave; tile < NN / 16; tile += gridDim.x * 4) {
        int node16 = tile * 16;
        f32x4 acc[4];
#pragma unroll
        for (int cf = 0; cf < 4; ++cf) acc[cf] = (f32x4){0.f, 0.f, 0.f, 0.f};
        const f16x8* xr = (const f16x8*)(h0 + (size_t)(node16 + (lane & 15)) * 128);
#pragma unroll
        for (int kf = 0; kf < 4; ++kf) {
            f16x8 af = xr[kf * 4 + g];
#pragma unroll
            for (int cf = 0; cf < 4; ++cf)
                acc[cf] =
                    __builtin_amdgcn_mfma_f32_16x16x32_f16(af, bf[kf][cf], acc[cf], 0, 0, 0);
        }
#pragma unroll
        for (int cf = 0; cf < 4; ++cf) {
#pragma unroll
            for (int r = 0; r < 4; ++r) {
                float v = acc[cf][r];
                float p = __shfl_xor(v, 1);
                if (!(lane & 1)) {
                    int node = node16 + g * 4 + r;
                    int ch = cf * 16 + (lane & 15);
                    *(unsigned int*)(y + (size_t)node * 64 + ch) = f2h(v, p);
                }
                s[cf] += v;
                s2[cf] += v * v;
            }
        }
    }
#pragma unroll
    for (int d = 16; d < 64; d <<= 1)
#pragma unroll
        for (int cf = 0; cf < 4; ++cf) {
            s[cf] += __shfl_xor(s[cf], d);
            s2[cf] += __shfl_xor(s2[cf], d);
        }
    __shared__ float lst[4][128];
    if (lane < 16) {
#pragma unroll
        for (int cf = 0; cf < 4; ++cf) {
            lst[wave][cf * 16 + lane] = s[cf];
            lst[wave][64 + cf * 16 + lane] = s2[cf];
        }
    }
    __syncthreads();
    if (threadIdx.x < 128)
        atomicAdd(&stats[threadIdx.x], lst[0][threadIdx.x] + lst[1][threadIdx.x] +
                                           lst[2][threadIdx.x] + lst[3][threadIdx.x]);
}

// ---------------- GEMM2 (MFMA, grid-stride): y2 = relu(bn1(y1)) @ W2 -> fp16 + stats ---

__global__ __launch_bounds__(256) void gemm2_kernel(const __half* __restrict__ y1,
                                                    const __half* __restrict__ Wpk,
                                                    const float* __restrict__ stats1,
                                                    const float* __restrict__ bg,
                                                    const float* __restrict__ bb,
                                                    __half* __restrict__ y2,
                                                    float* __restrict__ stats2) {
    __shared__ __half2 lsc2[32], lsh2[32];
    if (threadIdx.x < 32) {
        int p = threadIdx.x;
        int c0 = 2 * p, c1 = 2 * p + 1;
        float mu0 = stats1[c0] * (1.0f / NN);
        float var0 = stats1[64 + c0] * (1.0f / NN) - mu0 * mu0;
        float is0 = rsqrtf(var0 + BNEPS);
        float sc0 = bg[c0] * is0;
        float mu1 = stats1[c1] * (1.0f / NN);
        float var1 = stats1[64 + c1] * (1.0f / NN) - mu1 * mu1;
        float is1 = rsqrtf(var1 + BNEPS);
        float sc1 = bg[c1] * is1;
        lsc2[p] = __floats2half2_rn(sc0, sc1);
        lsh2[p] = __floats2half2_rn(bb[c0] - mu0 * sc0, bb[c1] - mu1 * sc1);
    }
    __syncthreads();
    int lane = threadIdx.x & 63, wave = threadIdx.x >> 6, g = lane >> 4;
    f16x8 bf[2][8];
    const f16x8* wp = (const f16x8*)Wpk;
#pragma unroll
    for (int kf = 0; kf < 2; ++kf)
#pragma unroll
        for (int cf = 0; cf < 8; ++cf) bf[kf][cf] = wp[(kf * 8 + cf) * 64 + lane];
    float s[8] = {0.f, 0.f, 0.f, 0.f, 0.f, 0.f, 0.f, 0.f};
    float s2[8] = {0.f, 0.f, 0.f, 0.f, 0.f, 0.f, 0.f, 0.f};
    for (int tile = blockIdx.x * 4 + wave; tile < NN / 16; tile += gridDim.x * 4) {
        int node16 = tile * 16;
        f32x4 acc[8];
#pragma unroll
        for (int cf = 0; cf < 8; ++cf) acc[cf] = (f32x4){0.f, 0.f, 0.f, 0.f};
        const f16x8* xr = (const f16x8*)(y1 + (size_t)(node16 + (lane & 15)) * 64);
#pragma unroll
        for (int kf = 0; kf < 2; ++kf) {
            f16x8 af = xr[kf * 4 + g];
            __half2* ap = (__half2*)&af;
            int p0 = kf * 16 + g * 4;
#pragma unroll
            for (int j = 0; j < 4; ++j)
                ap[j] = relu2(__hfma2(ap[j], lsc2[p0 + j], lsh2[p0 + j]));
#pragma unroll
            for (int cf = 0; cf < 8; ++cf)
                acc[cf] =
                    __builtin_amdgcn_mfma_f32_16x16x32_f16(af, bf[kf][cf], acc[cf], 0, 0, 0);
        }
#pragma unroll
        for (int cf = 0; cf < 8; ++cf) {
#pragma unroll
            for (int r = 0; r < 4; ++r) {
                float v = acc[cf][r];
                float p = __shfl_xor(v, 1);
                if (!(lane & 1)) {
                    int node = node16 + g * 4 + r;
                    int ch = cf * 16 + (lane & 15);
                    *(unsigned int*)(y2 + (size_t)node * 128 + ch) = f2h(v, p);
                }
                s[cf] += v;
                s2[cf] += v * v;
            }
        }
    }
#pragma unroll
    for (int d = 16; d < 64; d <<= 1)
#pragma unroll
        for (int cf = 0; cf < 8; ++cf) {
            s[cf] += __shfl_xor(s[cf], d);
            s2[cf] += __shfl_xor(s2[cf], d);
        }
    __shared__ float lst[4][256];
    if (lane < 16) {
#pragma unroll
        for (int cf = 0; cf < 8; ++cf) {
            lst[wave][cf * 16 + lane] = s[cf];
            lst[wave][128 + cf * 16 + lane] = s2[cf];
        }
    }
    __syncthreads();
    atomicAdd(&stats2[threadIdx.x], lst[0][threadIdx.x] + lst[1][threadIdx.x] +
                                        lst[2][threadIdx.x] + lst[3][threadIdx.x]);
}

// ---------------- last layer + fused mean-pool accumulation ----------------

__global__ void gemm_last_kernel(const __half* __restrict__ y1, const float* __restrict__ W,
                                 const float* __restrict__ stats1,
                                 const float* __restrict__ bg, const float* __restrict__ bb,
                                 const int* __restrict__ batch, float* __restrict__ pool) {
    __shared__ float lw[128];
    __shared__ float lsc[64], lsh[64];
    if (threadIdx.x < 128) lw[threadIdx.x] = W[threadIdx.x];
    if (threadIdx.x < 64) {
        int c = threadIdx.x;
        float mu = stats1[c] * (1.0f / NN);
        float var = stats1[64 + c] * (1.0f / NN) - mu * mu;
        float inv = rsqrtf(var + BNEPS);
        float sc = bg[c] * inv;
        lsc[c] = sc;
        lsh[c] = bb[c] - mu * sc;
    }
    __syncthreads();
    int n = blockIdx.x * 256 + threadIdx.x;
    int lane = threadIdx.x & 63;
    int gID = -1;
    float v0 = 0.f, v1 = 0.f, cnt = 0.f;
    if (n < NN) {
        float a0 = 0.f, a1 = 0.f;
        const uint4* row = (const uint4*)(y1 + (size_t)n * 64);
#pragma unroll
        for (int c8 = 0; c8 < 8; ++c8) {
            uint4 u = row[c8];
#pragma unroll
            for (int j = 0; j < 4; ++j) {
                unsigned int w = (j == 0) ? u.x : (j == 1) ? u.y : (j == 2) ? u.z : u.w;
                float2 f = h2f(w);
                int k = c8 * 8 + j * 2;
                float t0 = fmaxf(fmaf(f.x, lsc[k], lsh[k]), 0.f);
                float t1 = fmaxf(fmaf(f.y, lsc[k + 1], lsh[k + 1]), 0.f);
                a0 = fmaf(t0, lw[2 * k + 0], a0);
                a1 = fmaf(t0, lw[2 * k + 1], a1);
                a0 = fmaf(t1, lw[2 * k + 2], a0);
                a1 = fmaf(t1, lw[2 * k + 3], a1);
            }
        }
        gID = batch[n];
        v0 = fmaxf(a0, 0.f);
        v1 = fmaxf(a1, 0.f);
        cnt = 1.0f;
    }
    for (int d = 1; d < 64; d <<= 1) {
        int tg = __shfl_up(gID, d);
        float t0 = __shfl_up(v0, d);
        float t1 = __shfl_up(v1, d);
        float tc = __shfl_up(cnt, d);
        if (lane >= d && tg == gID) { v0 += t0; v1 += t1; cnt += tc; }
    }
    int gn = __shfl_down(gID, 1);
    bool lastv = (lane == 63) || (gn != gID);
    if (gID >= 0 && lastv) {
        atomicAdd(&pool[gID * 3 + 0], v0);
        atomicAdd(&pool[gID * 3 + 1], v1);
        atomicAdd(&pool[gID * 3 + 2], cnt);
    }
}

__global__ void pool_fin_kernel(const float* __restrict__ pool, float* __restrict__ out) {
    int t = threadIdx.x;
    if (t < GG * 2) {
        int g = t >> 1, j = t & 1;
        float cnt = pool[g * 3 + 2];
        out[t] = pool[g * 3 + j] / fmaxf(cnt, 1.0f);
    }
}

// ---------------- launch ----------------

extern "C" void kernel_launch(void* const* d_in, const int* in_sizes, int n_in,
                              void* d_out, int out_size, void* d_ws, size_t ws_size,
                              hipStream_t stream) {
    const float* x_in  = (const float*)d_in[0];
    const int*   ei    = (const int*)d_in[1];
    const int*   batch = (const int*)d_in[3];
    const float* W1    = (const float*)d_in[4];
    const float* bn1g  = (const float*)d_in[5];
    const float* bn1b  = (const float*)d_in[6];
    const float* W2    = (const float*)d_in[7];
    const float* bn2g  = (const float*)d_in[8];
    const float* bn2b  = (const float*)d_in[9];
    const float* Wlast = (const float*)d_in[10];
    const float* eps   = (const float*)d_in[11];
    float* out = (float*)d_out;

    char* ws = (char*)d_ws;
    size_t off = 0;
    auto alloc = [&](size_t bytes) -> char* {
        char* p = ws + off;
        off += (bytes + 255) & ~(size_t)255;
        return p;
    };
    // -- zeroed region first (one memset) --
    int*   deg      = (int*)alloc((size_t)NN * 4);
    float* statsall = (float*)alloc(16 * 256 * 4);  // slot s: [0..C) sum, [C..2C) sumsq
    float* pool     = (float*)alloc((size_t)GG * 3 * 4);
    size_t zero_len = off;
    // -- rest --
    int*            offs   = (int*)alloc((size_t)(NN + 1) * 4);
    int*            cursor = (int*)alloc((size_t)NN * 4);
    int*            bsum   = (int*)alloc(64 * 4);
    unsigned short* srcs   = (unsigned short*)alloc((size_t)EE * 2);
    __half*         X16    = (__half*)alloc((size_t)NN * 128 * 2);  // fp16 x_in
    __half*         A16    = (__half*)alloc((size_t)NN * 128 * 2);  // fp16 y2 (activated)
    __half*         B16    = (__half*)alloc((size_t)NN * 128 * 2);  // fp16 h0
    __half*         C16    = (__half*)alloc((size_t)NN * 64 * 2);   // fp16 raw y1
    __half*         Wpk1   = (__half*)alloc((size_t)7 * 8192 * 2);  // packed W1 frags
    __half*         Wpk2   = (__half*)alloc((size_t)6 * 8192 * 2);  // packed W2 frags
    (void)ws_size; (void)n_in; (void)in_sizes; (void)out_size;

    hipMemsetAsync(ws, 0, zero_len, stream);

    // CSR build (by dst); scatter + cvt + weight packs in ONE dispatch
    hist_kernel<<<(EE + 255) / 256, 256, 0, stream>>>(ei, deg);
    scan1_kernel<<<49, 1024, 0, stream>>>(deg, offs, bsum);
    scan3_kernel<<<49, 1024, 0, stream>>>(offs, cursor, bsum);
    const int SB = (EE + 255) / 256;
    const int CB = (NN * 16 + 255) / 256;
    scatter_prep_kernel<<<SB + CB + 28 + 24, 256, 0, stream>>>(ei, cursor, srcs, x_in, X16,
                                                               W1, Wpk1, W2, Wpk2);

    for (int i = 0; i < 7; ++i) {
        int s1 = 2 * i, s2 = 2 * i + 1;
        agg_kernel<<<(NN + 3) / 4, 256, 0, stream>>>(i == 0 ? X16 : A16, offs, srcs, eps, i,
                                                     B16);
        gemm1_kernel<<<256, 256, 0, stream>>>(B16, Wpk1 + (size_t)i * 8192, C16,
                                              statsall + s1 * 256);
        if (i < 6) {
            gemm2_kernel<<<256, 256, 0, stream>>>(C16, Wpk2 + (size_t)i * 8192,
                                                  statsall + s1 * 256, bn1g + i * 64,
                                                  bn1b + i * 64, A16, statsall + s2 * 256);
            bnrelu_kernel<<<2048, 256, 0, stream>>>(A16, statsall + s2 * 256,
                                                    bn2g + i * 128, bn2b + i * 128);
        } else {
            gemm_last_kernel<<<(NN + 255) / 256, 256, 0, stream>>>(
                C16, Wlast, statsall + s1 * 256, bn1g + i * 64, bn1b + i * 64, batch, pool);
        }
    }

    pool_fin_kernel<<<1, 128, 0, stream>>>(pool, out);
}